// Round 13
// baseline (69.567 us; speedup 1.0000x reference)
//
#include <hip/hip_runtime.h>
#include <hip/hip_bf16.h>

#define D 128
#define TM 32
#define PAD 8

typedef unsigned int u32;
typedef unsigned short u16;
typedef __attribute__((ext_vector_type(8))) short short8;
typedef __attribute__((ext_vector_type(4))) float f32x4;
typedef __attribute__((ext_vector_type(4))) unsigned int u32x4;
typedef __attribute__((ext_vector_type(4))) unsigned short u16x4;

static __device__ __forceinline__ u16 f2b(float x) {
  __hip_bfloat16 b = __float2bfloat16(x);
  return *reinterpret_cast<u16*>(&b);
}
static __device__ __forceinline__ float u2f(u32 x) { return __uint_as_float(x); }

// ---------- int8 fast path ----------

// Wt[c,k] = bf16(W[k,c])  (run once)
__global__ __launch_bounds__(256) void cvt_w(const float* __restrict__ W,
                                             u16* __restrict__ Wt) {
  int i = blockIdx.x * 256 + threadIdx.x;
  if (i >= D * D) return;
  int k = i >> 7, c = i & (D - 1);
  Wt[c * D + k] = f2b(W[k * D + c]);
}

// Yq[r][c] = int8(round(y[r][c] * 127/amax_r)),  ysc[r] = amax_r/127,
// y[r,:] = src_norm[r] * (X[r,:] @ W).  64-row tile per block (round-11 form).
__global__ __launch_bounds__(256) void gemm_xw(
    const float* __restrict__ X, const float* __restrict__ sn,
    const u16* __restrict__ Wt, signed char* __restrict__ Yq,
    float* __restrict__ ysc, int n) {
  __shared__ u16 Bsl[D][D + PAD];
  __shared__ u16 Asl[64][D + PAD];
  int tid = threadIdx.x;
  int r0 = blockIdx.x * 64;

#pragma unroll
  for (int p = 0; p < 8; ++p) {  // stage Wt (32 KB) - clean 16-B copies
    int t = p * 256 + tid;
    int r = t >> 4, c = (t & 15) << 3;
    *reinterpret_cast<uint4*>(&Bsl[r][c]) =
        *reinterpret_cast<const uint4*>(Wt + r * D + c);
  }
#pragma unroll
  for (int p = 0; p < 8; ++p) {  // stage A tile: f32 load, ns scale, cvt
    int idx = p * 256 + tid;
    int row = idx >> 5, c0 = (idx & 31) << 2;
    int gr = r0 + row;
    if (gr >= n) gr = n - 1;
    float ns = sn[gr];
    f32x4 v = *reinterpret_cast<const f32x4*>(X + (size_t)gr * D + c0);
    u16x4 o;
    o.x = f2b(v.x * ns); o.y = f2b(v.y * ns);
    o.z = f2b(v.z * ns); o.w = f2b(v.w * ns);
    *reinterpret_cast<u16x4*>(&Asl[row][c0]) = o;
  }
  __syncthreads();

  int wv = tid >> 6, lane = tid & 63;
  int lr = lane & 15, lg = lane >> 4;
  int arow = wv * 16 + lr;

  f32x4 acc[8] = {};
#pragma unroll
  for (int ks = 0; ks < 4; ++ks) {
    int k0 = ks * 32 + lg * 4;
    union { uint2 u[2]; short8 s; } pa;
    pa.u[0] = *reinterpret_cast<const uint2*>(&Asl[arow][k0]);
    pa.u[1] = *reinterpret_cast<const uint2*>(&Asl[arow][k0 + 16]);
#pragma unroll
    for (int nn = 0; nn < 8; ++nn) {
      union { uint2 u[2]; short8 s; } pb;
      pb.u[0] = *reinterpret_cast<const uint2*>(&Bsl[nn * 16 + lr][k0]);
      pb.u[1] = *reinterpret_cast<const uint2*>(&Bsl[nn * 16 + lr][k0 + 16]);
      acc[nn] = __builtin_amdgcn_mfma_f32_16x16x32_bf16(pa.s, pb.s, acc[nn], 0, 0, 0);
    }
  }

  __syncthreads();  // Asl reads done; repack result as bf16 rows
#pragma unroll
  for (int nn = 0; nn < 8; ++nn)
#pragma unroll
    for (int r = 0; r < 4; ++r)
      Asl[wv * 16 + lg * 4 + r][nn * 16 + lr] = f2b(acc[nn][r]);
  __syncthreads();

  // int8 quantization pass: 4 threads per row, 32 cols each.
  {
    int row = tid >> 2, qt = tid & 3;
    int gr = r0 + row;
    float vals[32];
    float amax = 0.f;
#pragma unroll
    for (int i = 0; i < 4; ++i) {
      uint4 w = *reinterpret_cast<const uint4*>(&Asl[row][qt * 32 + i * 8]);
      u32 ws[4] = {w.x, w.y, w.z, w.w};
#pragma unroll
      for (int h = 0; h < 4; ++h) {
        float v0 = u2f(ws[h] << 16);
        float v1 = u2f(ws[h] & 0xffff0000u);
        vals[i * 8 + h * 2 + 0] = v0;
        vals[i * 8 + h * 2 + 1] = v1;
        amax = fmaxf(amax, fmaxf(fabsf(v0), fabsf(v1)));
      }
    }
    amax = fmaxf(amax, __shfl_xor(amax, 1, 4));
    amax = fmaxf(amax, __shfl_xor(amax, 2, 4));
    float inv = amax > 0.f ? 127.0f / amax : 0.f;
    u32 pk[8];
#pragma unroll
    for (int i = 0; i < 8; ++i) {
      u32 b0 = (u32)((int)rintf(vals[i * 4 + 0] * inv)) & 0xffu;
      u32 b1 = (u32)((int)rintf(vals[i * 4 + 1] * inv)) & 0xffu;
      u32 b2 = (u32)((int)rintf(vals[i * 4 + 2] * inv)) & 0xffu;
      u32 b3 = (u32)((int)rintf(vals[i * 4 + 3] * inv)) & 0xffu;
      pk[i] = b0 | (b1 << 8) | (b2 << 16) | (b3 << 24);
    }
    if (gr < n) {
      u32x4 o0 = {pk[0], pk[1], pk[2], pk[3]};
      u32x4 o1 = {pk[4], pk[5], pk[6], pk[7]};
      u32* dst = reinterpret_cast<u32*>(Yq + (size_t)gr * D + qt * 32);
      __builtin_nontemporal_store(o0, reinterpret_cast<u32x4*>(dst));
      __builtin_nontemporal_store(o1, reinterpret_cast<u32x4*>(dst + 4));
      if (qt == 0) ysc[gr] = amax * (1.0f / 127.0f);
    }
  }
}

// decode one u32 (4 int8) into 4 named accumulators with scale sc
#define ACCW(w, sc, A0, A1, A2, A3)                         \
  A0 = fmaf(sc, (float)((int)((w) << 24) >> 24), A0);       \
  A1 = fmaf(sc, (float)((int)((w) << 16) >> 24), A1);       \
  A2 = fmaf(sc, (float)((int)((w) << 8) >> 24), A2);        \
  A3 = fmaf(sc, (float)((int)(w) >> 24), A3);

// decode a uint4 (16 int8) into a0..a15
#define ACCQ16(q, sc)                                       \
  ACCW((q).x, sc, a0, a1, a2, a3)                           \
  ACCW((q).y, sc, a4, a5, a6, a7)                           \
  ACCW((q).z, sc, a8, a9, a10, a11)                         \
  ACCW((q).w, sc, a12, a13, a14, a15)

// out[node,:] = dst_norm[node] * sum_e ysc[s]*Yq[s,:]  (f32 output)
// 8 lanes/node, 16 int8 (16 B) per lane -> 1 KB per wave load instr, 8
// outstanding rows per instr (2x round-12 MLP).
__global__ __launch_bounds__(256) void agg_final(
    const int* __restrict__ edge_ptr, const int* __restrict__ src_edges,
    const float* __restrict__ dst_norm, const signed char* __restrict__ Yq,
    const float* __restrict__ ysc, float* __restrict__ out, int n_nodes) {
  int gid = blockIdx.x * 256 + threadIdx.x;
  int node = gid >> 3;
  if (node >= n_nodes) return;
  int ll = threadIdx.x & 7;
  int fo = ll << 4;  // int8/f32 column offset (16 cols per lane)
  const signed char* base = Yq + fo;
  float a0 = 0, a1 = 0, a2 = 0, a3 = 0, a4 = 0, a5 = 0, a6 = 0, a7 = 0;
  float a8 = 0, a9 = 0, a10 = 0, a11 = 0, a12 = 0, a13 = 0, a14 = 0, a15 = 0;
  int e0 = edge_ptr[node], e1 = edge_ptr[node + 1];
  int e = e0;
  for (; e + 4 <= e1; e += 4) {
    int s0 = src_edges[e + 0], s1 = src_edges[e + 1];
    int s2 = src_edges[e + 2], s3 = src_edges[e + 3];
    uint4 q0 = *reinterpret_cast<const uint4*>(base + (size_t)s0 * D);
    uint4 q1 = *reinterpret_cast<const uint4*>(base + (size_t)s1 * D);
    uint4 q2 = *reinterpret_cast<const uint4*>(base + (size_t)s2 * D);
    uint4 q3 = *reinterpret_cast<const uint4*>(base + (size_t)s3 * D);
    float c0 = ysc[s0], c1 = ysc[s1], c2 = ysc[s2], c3 = ysc[s3];
    ACCQ16(q0, c0); ACCQ16(q1, c1); ACCQ16(q2, c2); ACCQ16(q3, c3);
  }
  for (; e < e1; ++e) {
    int s = src_edges[e];
    uint4 q = *reinterpret_cast<const uint4*>(base + (size_t)s * D);
    float c = ysc[s];
    ACCQ16(q, c);
  }
  float nd = dst_norm[node];
  f32x4 o0 = {a0 * nd, a1 * nd, a2 * nd, a3 * nd};
  f32x4 o1 = {a4 * nd, a5 * nd, a6 * nd, a7 * nd};
  f32x4 o2 = {a8 * nd, a9 * nd, a10 * nd, a11 * nd};
  f32x4 o3 = {a12 * nd, a13 * nd, a14 * nd, a15 * nd};
  float* dst = out + (size_t)node * D + fo;
  __builtin_nontemporal_store(o0, reinterpret_cast<f32x4*>(dst));
  __builtin_nontemporal_store(o1, reinterpret_cast<f32x4*>(dst + 4));
  __builtin_nontemporal_store(o2, reinterpret_cast<f32x4*>(dst + 8));
  __builtin_nontemporal_store(o3, reinterpret_cast<f32x4*>(dst + 12));
}

// ---------- f32 fallback path (known-good) ----------

__global__ __launch_bounds__(256) void agg_kernel(
    const int* __restrict__ edge_ptr, const int* __restrict__ src_edges,
    const float* __restrict__ src_norm, const float* __restrict__ dst_norm,
    const float* __restrict__ X, float* __restrict__ agg, int n_nodes) {
  int gid = blockIdx.x * 256 + threadIdx.x;
  int node = gid >> 5;
  if (node >= n_nodes) return;
  int fo = (gid & 31) << 2;
  int e0 = edge_ptr[node];
  int e1 = edge_ptr[node + 1];
  float ax = 0.f, ay = 0.f, az = 0.f, aw = 0.f;
  for (int e = e0; e < e1; ++e) {
    int s = src_edges[e];
    float ns = src_norm[s];
    float4 v = *reinterpret_cast<const float4*>(X + (size_t)s * D + fo);
    ax = fmaf(ns, v.x, ax); ay = fmaf(ns, v.y, ay);
    az = fmaf(ns, v.z, az); aw = fmaf(ns, v.w, aw);
  }
  float nd = dst_norm[node];
  float4 r = make_float4(ax * nd, ay * nd, az * nd, aw * nd);
  *reinterpret_cast<float4*>(agg + (size_t)node * D + fo) = r;
}

#define FMA4(acc, sv, wv)            \
  acc.x = fmaf(sv, wv.x, acc.x);     \
  acc.y = fmaf(sv, wv.y, acc.y);     \
  acc.z = fmaf(sv, wv.z, acc.z);     \
  acc.w = fmaf(sv, wv.w, acc.w);

__global__ __launch_bounds__(256) void gemm_kernel(
    float* __restrict__ io, const float* __restrict__ W, int n_rows) {
  __shared__ float Wl[D][D];
  __shared__ float Al[TM][D];
  int tid = threadIdx.x;
  for (int i = tid * 4; i < D * D; i += 1024) {
    *reinterpret_cast<float4*>(&Wl[0][0] + i) =
        *reinterpret_cast<const float4*>(W + i);
  }
  int row0 = blockIdx.x * TM;
  for (int i = tid * 4; i < TM * D; i += 1024) {
    int r = i >> 7, c = i & (D - 1);
    if (row0 + r < n_rows)
      *reinterpret_cast<float4*>(&Al[r][c]) =
          *reinterpret_cast<const float4*>(io + (size_t)(row0 + r) * D + c);
  }
  __syncthreads();

  int cg = (tid & 31) * 4;
  int rb = (tid >> 5) * 4;
  float4 acc0 = {0, 0, 0, 0}, acc1 = {0, 0, 0, 0};
  float4 acc2 = {0, 0, 0, 0}, acc3 = {0, 0, 0, 0};

#pragma unroll 4
  for (int k = 0; k < D; k += 4) {
    float4 w0 = *reinterpret_cast<const float4*>(&Wl[k + 0][cg]);
    float4 w1 = *reinterpret_cast<const float4*>(&Wl[k + 1][cg]);
    float4 w2 = *reinterpret_cast<const float4*>(&Wl[k + 2][cg]);
    float4 w3 = *reinterpret_cast<const float4*>(&Wl[k + 3][cg]);
    float4 a0 = *reinterpret_cast<const float4*>(&Al[rb + 0][k]);
    float4 a1 = *reinterpret_cast<const float4*>(&Al[rb + 1][k]);
    float4 a2 = *reinterpret_cast<const float4*>(&Al[rb + 2][k]);
    float4 a3 = *reinterpret_cast<const float4*>(&Al[rb + 3][k]);
    FMA4(acc0, a0.x, w0); FMA4(acc0, a0.y, w1); FMA4(acc0, a0.z, w2); FMA4(acc0, a0.w, w3);
    FMA4(acc1, a1.x, w0); FMA4(acc1, a1.y, w1); FMA4(acc1, a1.z, w2); FMA4(acc1, a1.w, w3);
    FMA4(acc2, a2.x, w0); FMA4(acc2, a2.y, w1); FMA4(acc2, a2.z, w2); FMA4(acc2, a2.w, w3);
    FMA4(acc3, a3.x, w0); FMA4(acc3, a3.y, w1); FMA4(acc3, a3.z, w2); FMA4(acc3, a3.w, w3);
  }

  int r0 = row0 + rb;
  if (r0 + 0 < n_rows) *reinterpret_cast<float4*>(io + (size_t)(r0 + 0) * D + cg) = acc0;
  if (r0 + 1 < n_rows) *reinterpret_cast<float4*>(io + (size_t)(r0 + 1) * D + cg) = acc1;
  if (r0 + 2 < n_rows) *reinterpret_cast<float4*>(io + (size_t)(r0 + 2) * D + cg) = acc2;
  if (r0 + 3 < n_rows) *reinterpret_cast<float4*>(io + (size_t)(r0 + 3) * D + cg) = acc3;
}

extern "C" void kernel_launch(void* const* d_in, const int* in_sizes, int n_in,
                              void* d_out, int out_size, void* d_ws, size_t ws_size,
                              hipStream_t stream) {
  const int* edge_ptr = (const int*)d_in[0];
  const int* src_edges = (const int*)d_in[1];
  const float* src_norm = (const float*)d_in[2];
  const float* dst_norm = (const float*)d_in[3];
  const float* X = (const float*)d_in[5];
  const float* W = (const float*)d_in[6];
  float* out = (float*)d_out;
  int n = in_sizes[2];  // src_norm_degs has N elements

  size_t need = (size_t)n * D + (size_t)n * sizeof(float) +
                (size_t)D * D * sizeof(u16);
  if (ws_size >= need) {
    signed char* Yq = (signed char*)d_ws;
    float* ysc = (float*)(Yq + (size_t)n * D);
    u16* Wt = (u16*)(ysc + n);
    cvt_w<<<(D * D + 255) / 256, 256, 0, stream>>>(W, Wt);
    gemm_xw<<<(n + 63) / 64, 256, 0, stream>>>(X, src_norm, Wt, Yq, ysc, n);
    agg_final<<<(n * 8 + 255) / 256, 256, 0, stream>>>(edge_ptr, src_edges,
                                                       dst_norm, Yq, ysc, out, n);
  } else {
    int blocks1 = (n * 32 + 255) / 256;
    agg_kernel<<<blocks1, 256, 0, stream>>>(edge_ptr, src_edges, src_norm,
                                            dst_norm, X, out, n);
    int blocks2 = (n + TM - 1) / TM;
    gemm_kernel<<<blocks2, 256, 0, stream>>>(out, W, n);
  }
}

// Round 14
// 63.802 us; speedup vs baseline: 1.0904x; 1.0904x over previous
//
#include <hip/hip_runtime.h>
#include <hip/hip_bf16.h>

#define D 128
#define TM 32
#define PAD 8

typedef unsigned int u32;
typedef unsigned short u16;
typedef __attribute__((ext_vector_type(8))) short short8;
typedef __attribute__((ext_vector_type(4))) float f32x4;
typedef __attribute__((ext_vector_type(4))) unsigned int u32x4;
typedef __attribute__((ext_vector_type(4))) unsigned short u16x4;

static __device__ __forceinline__ u16 f2b(float x) {
  __hip_bfloat16 b = __float2bfloat16(x);
  return *reinterpret_cast<u16*>(&b);
}
static __device__ __forceinline__ float u2f(u32 x) { return __uint_as_float(x); }

// ---------- int8 fast path ----------

// Wt[c,k] = bf16(W[k,c])  (run once)
__global__ __launch_bounds__(256) void cvt_w(const float* __restrict__ W,
                                             u16* __restrict__ Wt) {
  int i = blockIdx.x * 256 + threadIdx.x;
  if (i >= D * D) return;
  int k = i >> 7, c = i & (D - 1);
  Wt[c * D + k] = f2b(W[k * D + c]);
}

// Yq[r][c] = int8(round(y[r][c] * 127/amax_r)),  ysc[r] = amax_r/127,
// y[r,:] = src_norm[r] * (X[r,:] @ W).
// 512 threads, 128-row tile: LDS 69.6 KB -> 2 blocks/CU (16 waves/CU),
// Bsl staged once per 128 rows (half the r11 staging traffic).
__global__ __launch_bounds__(512) void gemm_xw(
    const float* __restrict__ X, const float* __restrict__ sn,
    const u16* __restrict__ Wt, signed char* __restrict__ Yq,
    float* __restrict__ ysc, int n) {
  __shared__ u16 Bsl[D][D + PAD];
  __shared__ u16 Asl[128][D + PAD];
  int tid = threadIdx.x;
  int r0 = blockIdx.x * 128;

#pragma unroll
  for (int p = 0; p < 4; ++p) {  // stage Wt (32 KB) - clean 16-B copies
    int t = p * 512 + tid;
    int r = t >> 4, c = (t & 15) << 3;
    *reinterpret_cast<uint4*>(&Bsl[r][c]) =
        *reinterpret_cast<const uint4*>(Wt + r * D + c);
  }
#pragma unroll
  for (int p = 0; p < 8; ++p) {  // stage A tile: f32 load, ns scale, cvt
    int idx = p * 512 + tid;
    int row = idx >> 5, c0 = (idx & 31) << 2;
    int gr = r0 + row;
    if (gr >= n) gr = n - 1;
    float ns = sn[gr];
    f32x4 v = *reinterpret_cast<const f32x4*>(X + (size_t)gr * D + c0);
    u16x4 o;
    o.x = f2b(v.x * ns); o.y = f2b(v.y * ns);
    o.z = f2b(v.z * ns); o.w = f2b(v.w * ns);
    *reinterpret_cast<u16x4*>(&Asl[row][c0]) = o;
  }
  __syncthreads();

  int wv = tid >> 6, lane = tid & 63;
  int lr = lane & 15, lg = lane >> 4;
  int arow = wv * 16 + lr;  // 8 waves x 16 rows = 128

  f32x4 acc[8] = {};
#pragma unroll
  for (int ks = 0; ks < 4; ++ks) {
    int k0 = ks * 32 + lg * 4;
    union { uint2 u[2]; short8 s; } pa;
    pa.u[0] = *reinterpret_cast<const uint2*>(&Asl[arow][k0]);
    pa.u[1] = *reinterpret_cast<const uint2*>(&Asl[arow][k0 + 16]);
#pragma unroll
    for (int nn = 0; nn < 8; ++nn) {
      union { uint2 u[2]; short8 s; } pb;
      pb.u[0] = *reinterpret_cast<const uint2*>(&Bsl[nn * 16 + lr][k0]);
      pb.u[1] = *reinterpret_cast<const uint2*>(&Bsl[nn * 16 + lr][k0 + 16]);
      acc[nn] = __builtin_amdgcn_mfma_f32_16x16x32_bf16(pa.s, pb.s, acc[nn], 0, 0, 0);
    }
  }

  __syncthreads();  // Asl reads done; repack result as bf16 rows
#pragma unroll
  for (int nn = 0; nn < 8; ++nn)
#pragma unroll
    for (int r = 0; r < 4; ++r)
      Asl[wv * 16 + lg * 4 + r][nn * 16 + lr] = f2b(acc[nn][r]);
  __syncthreads();

  // int8 quantization pass: 4 threads per row, 32 cols each (1 pass, 128 rows).
  {
    int row = tid >> 2, qt = tid & 3;
    int gr = r0 + row;
    float vals[32];
    float amax = 0.f;
#pragma unroll
    for (int i = 0; i < 4; ++i) {
      uint4 w = *reinterpret_cast<const uint4*>(&Asl[row][qt * 32 + i * 8]);
      u32 ws[4] = {w.x, w.y, w.z, w.w};
#pragma unroll
      for (int h = 0; h < 4; ++h) {
        float v0 = u2f(ws[h] << 16);
        float v1 = u2f(ws[h] & 0xffff0000u);
        vals[i * 8 + h * 2 + 0] = v0;
        vals[i * 8 + h * 2 + 1] = v1;
        amax = fmaxf(amax, fmaxf(fabsf(v0), fabsf(v1)));
      }
    }
    amax = fmaxf(amax, __shfl_xor(amax, 1, 4));
    amax = fmaxf(amax, __shfl_xor(amax, 2, 4));
    float inv = amax > 0.f ? 127.0f / amax : 0.f;
    u32 pk[8];
#pragma unroll
    for (int i = 0; i < 8; ++i) {
      u32 b0 = (u32)((int)rintf(vals[i * 4 + 0] * inv)) & 0xffu;
      u32 b1 = (u32)((int)rintf(vals[i * 4 + 1] * inv)) & 0xffu;
      u32 b2 = (u32)((int)rintf(vals[i * 4 + 2] * inv)) & 0xffu;
      u32 b3 = (u32)((int)rintf(vals[i * 4 + 3] * inv)) & 0xffu;
      pk[i] = b0 | (b1 << 8) | (b2 << 16) | (b3 << 24);
    }
    if (gr < n) {
      u32x4 o0 = {pk[0], pk[1], pk[2], pk[3]};
      u32x4 o1 = {pk[4], pk[5], pk[6], pk[7]};
      u32* dst = reinterpret_cast<u32*>(Yq + (size_t)gr * D + qt * 32);
      __builtin_nontemporal_store(o0, reinterpret_cast<u32x4*>(dst));
      __builtin_nontemporal_store(o1, reinterpret_cast<u32x4*>(dst + 4));
      if (qt == 0) ysc[gr] = amax * (1.0f / 127.0f);
    }
  }
}

// int8 decode-accumulate: 8 bytes of q (uint2), scale sc
#define ACCQ(q, sc)                                              \
  a0 = fmaf(sc, (float)((int)((q).x << 24) >> 24), a0);          \
  a1 = fmaf(sc, (float)((int)((q).x << 16) >> 24), a1);          \
  a2 = fmaf(sc, (float)((int)((q).x << 8) >> 24), a2);           \
  a3 = fmaf(sc, (float)((int)(q).x >> 24), a3);                  \
  a4 = fmaf(sc, (float)((int)((q).y << 24) >> 24), a4);          \
  a5 = fmaf(sc, (float)((int)((q).y << 16) >> 24), a5);          \
  a6 = fmaf(sc, (float)((int)(q).y << 8 >> 24), a6);             \
  a7 = fmaf(sc, (float)((int)(q).y >> 24), a7);

// out[node,:] = dst_norm[node] * sum_e ysc[s]*Yq[s,:]  (f32 output)
// Round-12 form: 16 lanes/node, 8 int8 (8 B) per lane, 4-deep unroll.
__global__ __launch_bounds__(256) void agg_final(
    const int* __restrict__ edge_ptr, const int* __restrict__ src_edges,
    const float* __restrict__ dst_norm, const signed char* __restrict__ Yq,
    const float* __restrict__ ysc, float* __restrict__ out, int n_nodes) {
  int gid = blockIdx.x * 256 + threadIdx.x;
  int node = gid >> 4;
  if (node >= n_nodes) return;
  int ll = threadIdx.x & 15;
  int fo = ll << 3;
  const signed char* base = Yq + fo;
  float a0 = 0, a1 = 0, a2 = 0, a3 = 0, a4 = 0, a5 = 0, a6 = 0, a7 = 0;
  int e0 = edge_ptr[node], e1 = edge_ptr[node + 1];
  int e = e0;
  for (; e + 4 <= e1; e += 4) {
    int s0 = src_edges[e + 0], s1 = src_edges[e + 1];
    int s2 = src_edges[e + 2], s3 = src_edges[e + 3];
    uint2 q0 = *reinterpret_cast<const uint2*>(base + (size_t)s0 * D);
    uint2 q1 = *reinterpret_cast<const uint2*>(base + (size_t)s1 * D);
    uint2 q2 = *reinterpret_cast<const uint2*>(base + (size_t)s2 * D);
    uint2 q3 = *reinterpret_cast<const uint2*>(base + (size_t)s3 * D);
    float c0 = ysc[s0], c1 = ysc[s1], c2 = ysc[s2], c3 = ysc[s3];
    ACCQ(q0, c0); ACCQ(q1, c1); ACCQ(q2, c2); ACCQ(q3, c3);
  }
  for (; e < e1; ++e) {
    int s = src_edges[e];
    uint2 q = *reinterpret_cast<const uint2*>(base + (size_t)s * D);
    float c = ysc[s];
    ACCQ(q, c);
  }
  float nd = dst_norm[node];
  f32x4 o0 = {a0 * nd, a1 * nd, a2 * nd, a3 * nd};
  f32x4 o1 = {a4 * nd, a5 * nd, a6 * nd, a7 * nd};
  float* dst = out + (size_t)node * D + fo;
  __builtin_nontemporal_store(o0, reinterpret_cast<f32x4*>(dst));
  __builtin_nontemporal_store(o1, reinterpret_cast<f32x4*>(dst + 4));
}

// ---------- f32 fallback path (known-good) ----------

__global__ __launch_bounds__(256) void agg_kernel(
    const int* __restrict__ edge_ptr, const int* __restrict__ src_edges,
    const float* __restrict__ src_norm, const float* __restrict__ dst_norm,
    const float* __restrict__ X, float* __restrict__ agg, int n_nodes) {
  int gid = blockIdx.x * 256 + threadIdx.x;
  int node = gid >> 5;
  if (node >= n_nodes) return;
  int fo = (gid & 31) << 2;
  int e0 = edge_ptr[node];
  int e1 = edge_ptr[node + 1];
  float ax = 0.f, ay = 0.f, az = 0.f, aw = 0.f;
  for (int e = e0; e < e1; ++e) {
    int s = src_edges[e];
    float ns = src_norm[s];
    float4 v = *reinterpret_cast<const float4*>(X + (size_t)s * D + fo);
    ax = fmaf(ns, v.x, ax); ay = fmaf(ns, v.y, ay);
    az = fmaf(ns, v.z, az); aw = fmaf(ns, v.w, aw);
  }
  float nd = dst_norm[node];
  float4 r = make_float4(ax * nd, ay * nd, az * nd, aw * nd);
  *reinterpret_cast<float4*>(agg + (size_t)node * D + fo) = r;
}

#define FMA4(acc, sv, wv)            \
  acc.x = fmaf(sv, wv.x, acc.x);     \
  acc.y = fmaf(sv, wv.y, acc.y);     \
  acc.z = fmaf(sv, wv.z, acc.z);     \
  acc.w = fmaf(sv, wv.w, acc.w);

__global__ __launch_bounds__(256) void gemm_kernel(
    float* __restrict__ io, const float* __restrict__ W, int n_rows) {
  __shared__ float Wl[D][D];
  __shared__ float Al[TM][D];
  int tid = threadIdx.x;
  for (int i = tid * 4; i < D * D; i += 1024) {
    *reinterpret_cast<float4*>(&Wl[0][0] + i) =
        *reinterpret_cast<const float4*>(W + i);
  }
  int row0 = blockIdx.x * TM;
  for (int i = tid * 4; i < TM * D; i += 1024) {
    int r = i >> 7, c = i & (D - 1);
    if (row0 + r < n_rows)
      *reinterpret_cast<float4*>(&Al[r][c]) =
          *reinterpret_cast<const float4*>(io + (size_t)(row0 + r) * D + c);
  }
  __syncthreads();

  int cg = (tid & 31) * 4;
  int rb = (tid >> 5) * 4;
  float4 acc0 = {0, 0, 0, 0}, acc1 = {0, 0, 0, 0};
  float4 acc2 = {0, 0, 0, 0}, acc3 = {0, 0, 0, 0};

#pragma unroll 4
  for (int k = 0; k < D; k += 4) {
    float4 w0 = *reinterpret_cast<const float4*>(&Wl[k + 0][cg]);
    float4 w1 = *reinterpret_cast<const float4*>(&Wl[k + 1][cg]);
    float4 w2 = *reinterpret_cast<const float4*>(&Wl[k + 2][cg]);
    float4 w3 = *reinterpret_cast<const float4*>(&Wl[k + 3][cg]);
    float4 a0 = *reinterpret_cast<const float4*>(&Al[rb + 0][k]);
    float4 a1 = *reinterpret_cast<const float4*>(&Al[rb + 1][k]);
    float4 a2 = *reinterpret_cast<const float4*>(&Al[rb + 2][k]);
    float4 a3 = *reinterpret_cast<const float4*>(&Al[rb + 3][k]);
    FMA4(acc0, a0.x, w0); FMA4(acc0, a0.y, w1); FMA4(acc0, a0.z, w2); FMA4(acc0, a0.w, w3);
    FMA4(acc1, a1.x, w0); FMA4(acc1, a1.y, w1); FMA4(acc1, a1.z, w2); FMA4(acc1, a1.w, w3);
    FMA4(acc2, a2.x, w0); FMA4(acc2, a2.y, w1); FMA4(acc2, a2.z, w2); FMA4(acc2, a2.w, w3);
    FMA4(acc3, a3.x, w0); FMA4(acc3, a3.y, w1); FMA4(acc3, a3.z, w2); FMA4(acc3, a3.w, w3);
  }

  int r0 = row0 + rb;
  if (r0 + 0 < n_rows) *reinterpret_cast<float4*>(io + (size_t)(r0 + 0) * D + cg) = acc0;
  if (r0 + 1 < n_rows) *reinterpret_cast<float4*>(io + (size_t)(r0 + 1) * D + cg) = acc1;
  if (r0 + 2 < n_rows) *reinterpret_cast<float4*>(io + (size_t)(r0 + 2) * D + cg) = acc2;
  if (r0 + 3 < n_rows) *reinterpret_cast<float4*>(io + (size_t)(r0 + 3) * D + cg) = acc3;
}

extern "C" void kernel_launch(void* const* d_in, const int* in_sizes, int n_in,
                              void* d_out, int out_size, void* d_ws, size_t ws_size,
                              hipStream_t stream) {
  const int* edge_ptr = (const int*)d_in[0];
  const int* src_edges = (const int*)d_in[1];
  const float* src_norm = (const float*)d_in[2];
  const float* dst_norm = (const float*)d_in[3];
  const float* X = (const float*)d_in[5];
  const float* W = (const float*)d_in[6];
  float* out = (float*)d_out;
  int n = in_sizes[2];  // src_norm_degs has N elements

  size_t need = (size_t)n * D + (size_t)n * sizeof(float) +
                (size_t)D * D * sizeof(u16);
  if (ws_size >= need) {
    signed char* Yq = (signed char*)d_ws;
    float* ysc = (float*)(Yq + (size_t)n * D);
    u16* Wt = (u16*)(ysc + n);
    cvt_w<<<(D * D + 255) / 256, 256, 0, stream>>>(W, Wt);
    gemm_xw<<<(n + 127) / 128, 512, 0, stream>>>(X, src_norm, Wt, Yq, ysc, n);
    agg_final<<<(n * 16 + 255) / 256, 256, 0, stream>>>(edge_ptr, src_edges,
                                                        dst_norm, Yq, ysc, out, n);
  } else {
    int blocks1 = (n * 32 + 255) / 256;
    agg_kernel<<<blocks1, 256, 0, stream>>>(edge_ptr, src_edges, src_norm,
                                            dst_norm, X, out, n);
    int blocks2 = (n + TM - 1) / TM;
    gemm_kernel<<<blocks2, 256, 0, stream>>>(out, W, n);
  }
}

// Round 15
// 62.943 us; speedup vs baseline: 1.1052x; 1.0136x over previous
//
#include <hip/hip_runtime.h>
#include <hip/hip_bf16.h>

#define D 128
#define TM 32
#define PAD 8

typedef unsigned int u32;
typedef unsigned short u16;
typedef __attribute__((ext_vector_type(8))) short short8;
typedef __attribute__((ext_vector_type(4))) float f32x4;
typedef __attribute__((ext_vector_type(4))) unsigned int u32x4;
typedef __attribute__((ext_vector_type(4))) unsigned short u16x4;

static __device__ __forceinline__ u16 f2b(float x) {
  __hip_bfloat16 b = __float2bfloat16(x);
  return *reinterpret_cast<u16*>(&b);
}
static __device__ __forceinline__ float u2f(u32 x) { return __uint_as_float(x); }

// ---------- int8 fast path ----------

// Wt[c,k] = bf16(W[k,c])  (run once)
__global__ __launch_bounds__(256) void cvt_w(const float* __restrict__ W,
                                             u16* __restrict__ Wt) {
  int i = blockIdx.x * 256 + threadIdx.x;
  if (i >= D * D) return;
  int k = i >> 7, c = i & (D - 1);
  Wt[c * D + k] = f2b(W[k * D + c]);
}

// Yq[r][c] = int8(round(y[r][c]*127/amax_r)), ysc[r] = amax_r/127,
// y[r,:] = src_norm[r] * (X[r,:] @ W).
// 512 threads / 128-row tile. A-fragments loaded DIRECTLY from global X
// (in-register ns-scale + bf16 pack; per-wave coalesced: 16 rows x 1 line
// per ks). B from LDS Bsl. Quant amax in-register via shfl_xor over the
// 16-lane row group; int8 repack through small Qls for coalesced stores.
__global__ __launch_bounds__(512) void gemm_xw(
    const float* __restrict__ X, const float* __restrict__ sn,
    const u16* __restrict__ Wt, signed char* __restrict__ Yq,
    float* __restrict__ ysc, int n) {
  __shared__ u16 Bsl[D][D + PAD];           // 34.8 KB
  __shared__ signed char Qls[128][D + 16];  // 18.4 KB, 16B-aligned rows
  int tid = threadIdx.x;
  int r0 = blockIdx.x * 128;

#pragma unroll
  for (int p = 0; p < 4; ++p) {  // stage Wt (32 KB) - clean 16-B copies
    int t = p * 512 + tid;
    int r = t >> 4, c = (t & 15) << 3;
    *reinterpret_cast<uint4*>(&Bsl[r][c]) =
        *reinterpret_cast<const uint4*>(Wt + r * D + c);
  }

  int wv = tid >> 6, lane = tid & 63;
  int lr = lane & 15, lg = lane >> 4;
  int arow = wv * 16 + lr;  // 8 waves x 16 rows = 128
  int gr = r0 + arow;
  int grc = gr < n ? gr : n - 1;
  float ns = sn[grc];
  const float* xrow = X + (size_t)grc * D;

  __syncthreads();

  f32x4 acc[8] = {};
#pragma unroll
  for (int ks = 0; ks < 4; ++ks) {
    int k0 = ks * 32 + lg * 4;
    f32x4 xa = *reinterpret_cast<const f32x4*>(xrow + k0);
    f32x4 xb = *reinterpret_cast<const f32x4*>(xrow + k0 + 16);
    union { u16 h[8]; short8 s; } pa;
    pa.h[0] = f2b(xa.x * ns); pa.h[1] = f2b(xa.y * ns);
    pa.h[2] = f2b(xa.z * ns); pa.h[3] = f2b(xa.w * ns);
    pa.h[4] = f2b(xb.x * ns); pa.h[5] = f2b(xb.y * ns);
    pa.h[6] = f2b(xb.z * ns); pa.h[7] = f2b(xb.w * ns);
#pragma unroll
    for (int nn = 0; nn < 8; ++nn) {
      union { uint2 u[2]; short8 s; } pb;
      pb.u[0] = *reinterpret_cast<const uint2*>(&Bsl[nn * 16 + lr][k0]);
      pb.u[1] = *reinterpret_cast<const uint2*>(&Bsl[nn * 16 + lr][k0 + 16]);
      acc[nn] = __builtin_amdgcn_mfma_f32_16x16x32_bf16(pa.s, pb.s, acc[nn], 0, 0, 0);
    }
  }

  // In-register quant: lane holds rows {wv*16+lg*4+r}, cols {nn*16+lr}.
  // Row amax = reduce over the 16 lanes sharing lg (lanes lg*16..lg*16+15).
#pragma unroll
  for (int r = 0; r < 4; ++r) {
    float amax = 0.f;
#pragma unroll
    for (int nn = 0; nn < 8; ++nn) amax = fmaxf(amax, fabsf(acc[nn][r]));
    amax = fmaxf(amax, __shfl_xor(amax, 1, 16));
    amax = fmaxf(amax, __shfl_xor(amax, 2, 16));
    amax = fmaxf(amax, __shfl_xor(amax, 4, 16));
    amax = fmaxf(amax, __shfl_xor(amax, 8, 16));
    float inv = amax > 0.f ? 127.0f / amax : 0.f;
    int wrow = wv * 16 + lg * 4 + r;
#pragma unroll
    for (int nn = 0; nn < 8; ++nn)
      Qls[wrow][nn * 16 + lr] = (signed char)(int)rintf(acc[nn][r] * inv);
    if (lr == 0) {
      int grow = r0 + wrow;
      if (grow < n) ysc[grow] = amax * (1.0f / 127.0f);
    }
  }
  __syncthreads();

  // Coalesced Yq stores: 4 threads/row, 32 B each.
  {
    int row = tid >> 2, q = tid & 3;
    int gr2 = r0 + row;
    if (gr2 < n) {
      u32x4 o0 = *reinterpret_cast<const u32x4*>(&Qls[row][q * 32]);
      u32x4 o1 = *reinterpret_cast<const u32x4*>(&Qls[row][q * 32 + 16]);
      u32* dst = reinterpret_cast<u32*>(Yq + (size_t)gr2 * D + q * 32);
      __builtin_nontemporal_store(o0, reinterpret_cast<u32x4*>(dst));
      __builtin_nontemporal_store(o1, reinterpret_cast<u32x4*>(dst + 4));
    }
  }
}

// int8 decode-accumulate: 8 bytes of q (uint2), scale sc
#define ACCQ(q, sc)                                              \
  a0 = fmaf(sc, (float)((int)((q).x << 24) >> 24), a0);          \
  a1 = fmaf(sc, (float)((int)((q).x << 16) >> 24), a1);          \
  a2 = fmaf(sc, (float)((int)((q).x << 8) >> 24), a2);           \
  a3 = fmaf(sc, (float)((int)(q).x >> 24), a3);                  \
  a4 = fmaf(sc, (float)((int)((q).y << 24) >> 24), a4);          \
  a5 = fmaf(sc, (float)((int)((q).y << 16) >> 24), a5);          \
  a6 = fmaf(sc, (float)((int)(q).y << 8 >> 24), a6);             \
  a7 = fmaf(sc, (float)((int)(q).y >> 24), a7);

// out[node,:] = dst_norm[node] * sum_e ysc[s]*Yq[s,:]  (f32 output)
// Round-12 form (measured 40.2 us): 16 lanes/node, 8 B/lane, 4-deep unroll.
__global__ __launch_bounds__(256) void agg_final(
    const int* __restrict__ edge_ptr, const int* __restrict__ src_edges,
    const float* __restrict__ dst_norm, const signed char* __restrict__ Yq,
    const float* __restrict__ ysc, float* __restrict__ out, int n_nodes) {
  int gid = blockIdx.x * 256 + threadIdx.x;
  int node = gid >> 4;
  if (node >= n_nodes) return;
  int ll = threadIdx.x & 15;
  int fo = ll << 3;
  const signed char* base = Yq + fo;
  float a0 = 0, a1 = 0, a2 = 0, a3 = 0, a4 = 0, a5 = 0, a6 = 0, a7 = 0;
  int e0 = edge_ptr[node], e1 = edge_ptr[node + 1];
  int e = e0;
  for (; e + 4 <= e1; e += 4) {
    int s0 = src_edges[e + 0], s1 = src_edges[e + 1];
    int s2 = src_edges[e + 2], s3 = src_edges[e + 3];
    uint2 q0 = *reinterpret_cast<const uint2*>(base + (size_t)s0 * D);
    uint2 q1 = *reinterpret_cast<const uint2*>(base + (size_t)s1 * D);
    uint2 q2 = *reinterpret_cast<const uint2*>(base + (size_t)s2 * D);
    uint2 q3 = *reinterpret_cast<const uint2*>(base + (size_t)s3 * D);
    float c0 = ysc[s0], c1 = ysc[s1], c2 = ysc[s2], c3 = ysc[s3];
    ACCQ(q0, c0); ACCQ(q1, c1); ACCQ(q2, c2); ACCQ(q3, c3);
  }
  for (; e < e1; ++e) {
    int s = src_edges[e];
    uint2 q = *reinterpret_cast<const uint2*>(base + (size_t)s * D);
    float c = ysc[s];
    ACCQ(q, c);
  }
  float nd = dst_norm[node];
  f32x4 o0 = {a0 * nd, a1 * nd, a2 * nd, a3 * nd};
  f32x4 o1 = {a4 * nd, a5 * nd, a6 * nd, a7 * nd};
  float* dst = out + (size_t)node * D + fo;
  __builtin_nontemporal_store(o0, reinterpret_cast<f32x4*>(dst));
  __builtin_nontemporal_store(o1, reinterpret_cast<f32x4*>(dst + 4));
}

// ---------- f32 fallback path (known-good) ----------

__global__ __launch_bounds__(256) void agg_kernel(
    const int* __restrict__ edge_ptr, const int* __restrict__ src_edges,
    const float* __restrict__ src_norm, const float* __restrict__ dst_norm,
    const float* __restrict__ X, float* __restrict__ agg, int n_nodes) {
  int gid = blockIdx.x * 256 + threadIdx.x;
  int node = gid >> 5;
  if (node >= n_nodes) return;
  int fo = (gid & 31) << 2;
  int e0 = edge_ptr[node];
  int e1 = edge_ptr[node + 1];
  float ax = 0.f, ay = 0.f, az = 0.f, aw = 0.f;
  for (int e = e0; e < e1; ++e) {
    int s = src_edges[e];
    float ns = src_norm[s];
    float4 v = *reinterpret_cast<const float4*>(X + (size_t)s * D + fo);
    ax = fmaf(ns, v.x, ax); ay = fmaf(ns, v.y, ay);
    az = fmaf(ns, v.z, az); aw = fmaf(ns, v.w, aw);
  }
  float nd = dst_norm[node];
  float4 r = make_float4(ax * nd, ay * nd, az * nd, aw * nd);
  *reinterpret_cast<float4*>(agg + (size_t)node * D + fo) = r;
}

#define FMA4(acc, sv, wv)            \
  acc.x = fmaf(sv, wv.x, acc.x);     \
  acc.y = fmaf(sv, wv.y, acc.y);     \
  acc.z = fmaf(sv, wv.z, acc.z);     \
  acc.w = fmaf(sv, wv.w, acc.w);

__global__ __launch_bounds__(256) void gemm_kernel(
    float* __restrict__ io, const float* __restrict__ W, int n_rows) {
  __shared__ float Wl[D][D];
  __shared__ float Al[TM][D];
  int tid = threadIdx.x;
  for (int i = tid * 4; i < D * D; i += 1024) {
    *reinterpret_cast<float4*>(&Wl[0][0] + i) =
        *reinterpret_cast<const float4*>(W + i);
  }
  int row0 = blockIdx.x * TM;
  for (int i = tid * 4; i < TM * D; i += 1024) {
    int r = i >> 7, c = i & (D - 1);
    if (row0 + r < n_rows)
      *reinterpret_cast<float4*>(&Al[r][c]) =
          *reinterpret_cast<const float4*>(io + (size_t)(row0 + r) * D + c);
  }
  __syncthreads();

  int cg = (tid & 31) * 4;
  int rb = (tid >> 5) * 4;
  float4 acc0 = {0, 0, 0, 0}, acc1 = {0, 0, 0, 0};
  float4 acc2 = {0, 0, 0, 0}, acc3 = {0, 0, 0, 0};

#pragma unroll 4
  for (int k = 0; k < D; k += 4) {
    float4 w0 = *reinterpret_cast<const float4*>(&Wl[k + 0][cg]);
    float4 w1 = *reinterpret_cast<const float4*>(&Wl[k + 1][cg]);
    float4 w2 = *reinterpret_cast<const float4*>(&Wl[k + 2][cg]);
    float4 w3 = *reinterpret_cast<const float4*>(&Wl[k + 3][cg]);
    float4 a0 = *reinterpret_cast<const float4*>(&Al[rb + 0][k]);
    float4 a1 = *reinterpret_cast<const float4*>(&Al[rb + 1][k]);
    float4 a2 = *reinterpret_cast<const float4*>(&Al[rb + 2][k]);
    float4 a3 = *reinterpret_cast<const float4*>(&Al[rb + 3][k]);
    FMA4(acc0, a0.x, w0); FMA4(acc0, a0.y, w1); FMA4(acc0, a0.z, w2); FMA4(acc0, a0.w, w3);
    FMA4(acc1, a1.x, w0); FMA4(acc1, a1.y, w1); FMA4(acc1, a1.z, w2); FMA4(acc1, a1.w, w3);
    FMA4(acc2, a2.x, w0); FMA4(acc2, a2.y, w1); FMA4(acc2, a2.z, w2); FMA4(acc2, a2.w, w3);
    FMA4(acc3, a3.x, w0); FMA4(acc3, a3.y, w1); FMA4(acc3, a3.z, w2); FMA4(acc3, a3.w, w3);
  }

  int r0 = row0 + rb;
  if (r0 + 0 < n_rows) *reinterpret_cast<float4*>(io + (size_t)(r0 + 0) * D + cg) = acc0;
  if (r0 + 1 < n_rows) *reinterpret_cast<float4*>(io + (size_t)(r0 + 1) * D + cg) = acc1;
  if (r0 + 2 < n_rows) *reinterpret_cast<float4*>(io + (size_t)(r0 + 2) * D + cg) = acc2;
  if (r0 + 3 < n_rows) *reinterpret_cast<float4*>(io + (size_t)(r0 + 3) * D + cg) = acc3;
}

extern "C" void kernel_launch(void* const* d_in, const int* in_sizes, int n_in,
                              void* d_out, int out_size, void* d_ws, size_t ws_size,
                              hipStream_t stream) {
  const int* edge_ptr = (const int*)d_in[0];
  const int* src_edges = (const int*)d_in[1];
  const float* src_norm = (const float*)d_in[2];
  const float* dst_norm = (const float*)d_in[3];
  const float* X = (const float*)d_in[5];
  const float* W = (const float*)d_in[6];
  float* out = (float*)d_out;
  int n = in_sizes[2];  // src_norm_degs has N elements

  size_t need = (size_t)n * D + (size_t)n * sizeof(float) +
                (size_t)D * D * sizeof(u16);
  if (ws_size >= need) {
    signed char* Yq = (signed char*)d_ws;
    float* ysc = (float*)(Yq + (size_t)n * D);
    u16* Wt = (u16*)(ysc + n);
    cvt_w<<<(D * D + 255) / 256, 256, 0, stream>>>(W, Wt);
    gemm_xw<<<(n + 127) / 128, 512, 0, stream>>>(X, src_norm, Wt, Yq, ysc, n);
    agg_final<<<(n * 16 + 255) / 256, 256, 0, stream>>>(edge_ptr, src_edges,
                                                        dst_norm, Yq, ysc, out, n);
  } else {
    int blocks1 = (n * 32 + 255) / 256;
    agg_kernel<<<blocks1, 256, 0, stream>>>(edge_ptr, src_edges, src_norm,
                                            dst_norm, X, out, n);
    int blocks2 = (n + TM - 1) / TM;
    gemm_kernel<<<blocks2, 256, 0, stream>>>(out, W, n);
  }
}

// Round 16
// 60.872 us; speedup vs baseline: 1.1428x; 1.0340x over previous
//
#include <hip/hip_runtime.h>
#include <hip/hip_bf16.h>

#define D 128
#define TM 32
#define PAD 8

typedef unsigned int u32;
typedef unsigned short u16;
typedef __attribute__((ext_vector_type(8))) short short8;
typedef __attribute__((ext_vector_type(4))) float f32x4;
typedef __attribute__((ext_vector_type(4))) unsigned int u32x4;
typedef __attribute__((ext_vector_type(4))) unsigned short u16x4;

static __device__ __forceinline__ u16 f2b(float x) {
  __hip_bfloat16 b = __float2bfloat16(x);
  return *reinterpret_cast<u16*>(&b);
}
static __device__ __forceinline__ float u2f(u32 x) { return __uint_as_float(x); }

// ---------- int8 fast path ----------

// Wt[c,k] = bf16(W[k,c])  (run once)
__global__ __launch_bounds__(256) void cvt_w(const float* __restrict__ W,
                                             u16* __restrict__ Wt) {
  int i = blockIdx.x * 256 + threadIdx.x;
  if (i >= D * D) return;
  int k = i >> 7, c = i & (D - 1);
  Wt[c * D + k] = f2b(W[k * D + c]);
}

// Yq[r][c] = int8(round(y[r][c] * 127/amax_r)),  ysc[r] = amax_r/127,
// y[r,:] = src_norm[r] * (X[r,:] @ W).  Round-11 measured-best form:
// 256 threads / 64-row tile, Bsl + Asl in LDS (52 KB).
__global__ __launch_bounds__(256) void gemm_xw(
    const float* __restrict__ X, const float* __restrict__ sn,
    const u16* __restrict__ Wt, signed char* __restrict__ Yq,
    float* __restrict__ ysc, int n) {
  __shared__ u16 Bsl[D][D + PAD];
  __shared__ u16 Asl[64][D + PAD];
  int tid = threadIdx.x;
  int r0 = blockIdx.x * 64;

#pragma unroll
  for (int p = 0; p < 8; ++p) {  // stage Wt (32 KB) - clean 16-B copies
    int t = p * 256 + tid;
    int r = t >> 4, c = (t & 15) << 3;
    *reinterpret_cast<uint4*>(&Bsl[r][c]) =
        *reinterpret_cast<const uint4*>(Wt + r * D + c);
  }
#pragma unroll
  for (int p = 0; p < 8; ++p) {  // stage A tile: f32 load, ns scale, cvt
    int idx = p * 256 + tid;
    int row = idx >> 5, c0 = (idx & 31) << 2;
    int gr = r0 + row;
    if (gr >= n) gr = n - 1;
    float ns = sn[gr];
    f32x4 v = *reinterpret_cast<const f32x4*>(X + (size_t)gr * D + c0);
    u16x4 o;
    o.x = f2b(v.x * ns); o.y = f2b(v.y * ns);
    o.z = f2b(v.z * ns); o.w = f2b(v.w * ns);
    *reinterpret_cast<u16x4*>(&Asl[row][c0]) = o;
  }
  __syncthreads();

  int wv = tid >> 6, lane = tid & 63;
  int lr = lane & 15, lg = lane >> 4;
  int arow = wv * 16 + lr;

  f32x4 acc[8] = {};
#pragma unroll
  for (int ks = 0; ks < 4; ++ks) {
    int k0 = ks * 32 + lg * 4;
    union { uint2 u[2]; short8 s; } pa;
    pa.u[0] = *reinterpret_cast<const uint2*>(&Asl[arow][k0]);
    pa.u[1] = *reinterpret_cast<const uint2*>(&Asl[arow][k0 + 16]);
#pragma unroll
    for (int nn = 0; nn < 8; ++nn) {
      union { uint2 u[2]; short8 s; } pb;
      pb.u[0] = *reinterpret_cast<const uint2*>(&Bsl[nn * 16 + lr][k0]);
      pb.u[1] = *reinterpret_cast<const uint2*>(&Bsl[nn * 16 + lr][k0 + 16]);
      acc[nn] = __builtin_amdgcn_mfma_f32_16x16x32_bf16(pa.s, pb.s, acc[nn], 0, 0, 0);
    }
  }

  __syncthreads();  // Asl reads done; repack result as bf16 rows
#pragma unroll
  for (int nn = 0; nn < 8; ++nn)
#pragma unroll
    for (int r = 0; r < 4; ++r)
      Asl[wv * 16 + lg * 4 + r][nn * 16 + lr] = f2b(acc[nn][r]);
  __syncthreads();

  // int8 quantization pass: 4 threads per row, 32 cols each.
  {
    int row = tid >> 2, qt = tid & 3;
    int gr = r0 + row;
    float vals[32];
    float amax = 0.f;
#pragma unroll
    for (int i = 0; i < 4; ++i) {
      uint4 w = *reinterpret_cast<const uint4*>(&Asl[row][qt * 32 + i * 8]);
      u32 ws[4] = {w.x, w.y, w.z, w.w};
#pragma unroll
      for (int h = 0; h < 4; ++h) {
        float v0 = u2f(ws[h] << 16);
        float v1 = u2f(ws[h] & 0xffff0000u);
        vals[i * 8 + h * 2 + 0] = v0;
        vals[i * 8 + h * 2 + 1] = v1;
        amax = fmaxf(amax, fmaxf(fabsf(v0), fabsf(v1)));
      }
    }
    amax = fmaxf(amax, __shfl_xor(amax, 1, 4));
    amax = fmaxf(amax, __shfl_xor(amax, 2, 4));
    float inv = amax > 0.f ? 127.0f / amax : 0.f;
    u32 pk[8];
#pragma unroll
    for (int i = 0; i < 8; ++i) {
      u32 b0 = (u32)((int)rintf(vals[i * 4 + 0] * inv)) & 0xffu;
      u32 b1 = (u32)((int)rintf(vals[i * 4 + 1] * inv)) & 0xffu;
      u32 b2 = (u32)((int)rintf(vals[i * 4 + 2] * inv)) & 0xffu;
      u32 b3 = (u32)((int)rintf(vals[i * 4 + 3] * inv)) & 0xffu;
      pk[i] = b0 | (b1 << 8) | (b2 << 16) | (b3 << 24);
    }
    if (gr < n) {
      u32x4 o0 = {pk[0], pk[1], pk[2], pk[3]};
      u32x4 o1 = {pk[4], pk[5], pk[6], pk[7]};
      u32* dst = reinterpret_cast<u32*>(Yq + (size_t)gr * D + qt * 32);
      __builtin_nontemporal_store(o0, reinterpret_cast<u32x4*>(dst));
      __builtin_nontemporal_store(o1, reinterpret_cast<u32x4*>(dst + 4));
      if (qt == 0) ysc[gr] = amax * (1.0f / 127.0f);
    }
  }
}

// int8 decode-accumulate: 8 bytes of q (uint2), scale sc
#define ACCQ(q, sc)                                              \
  a0 = fmaf(sc, (float)((int)((q).x << 24) >> 24), a0);          \
  a1 = fmaf(sc, (float)((int)((q).x << 16) >> 24), a1);          \
  a2 = fmaf(sc, (float)((int)((q).x << 8) >> 24), a2);           \
  a3 = fmaf(sc, (float)((int)(q).x >> 24), a3);                  \
  a4 = fmaf(sc, (float)((int)((q).y << 24) >> 24), a4);          \
  a5 = fmaf(sc, (float)((int)((q).y << 16) >> 24), a5);          \
  a6 = fmaf(sc, (float)((int)(q).y << 8 >> 24), a6);             \
  a7 = fmaf(sc, (float)((int)(q).y >> 24), a7);

// out[node,:] = dst_norm[node] * sum_e ysc[s]*Yq[s,:]  (f32 output)
// r12 geometry (16 lanes/node, 8 B/lane) with 8-deep load batching.
__global__ __launch_bounds__(256) void agg_final(
    const int* __restrict__ edge_ptr, const int* __restrict__ src_edges,
    const float* __restrict__ dst_norm, const signed char* __restrict__ Yq,
    const float* __restrict__ ysc, float* __restrict__ out, int n_nodes) {
  int gid = blockIdx.x * 256 + threadIdx.x;
  int node = gid >> 4;
  if (node >= n_nodes) return;
  int ll = threadIdx.x & 15;
  int fo = ll << 3;
  const signed char* base = Yq + fo;
  float a0 = 0, a1 = 0, a2 = 0, a3 = 0, a4 = 0, a5 = 0, a6 = 0, a7 = 0;
  int e0 = edge_ptr[node], e1 = edge_ptr[node + 1];
  int e = e0;
  for (; e + 8 <= e1; e += 8) {
    int s[8];
#pragma unroll
    for (int j = 0; j < 8; ++j) s[j] = src_edges[e + j];
    uint2 q[8];
#pragma unroll
    for (int j = 0; j < 8; ++j)
      q[j] = *reinterpret_cast<const uint2*>(base + (size_t)s[j] * D);
    float c[8];
#pragma unroll
    for (int j = 0; j < 8; ++j) c[j] = ysc[s[j]];
#pragma unroll
    for (int j = 0; j < 8; ++j) { ACCQ(q[j], c[j]); }
  }
  for (; e + 4 <= e1; e += 4) {
    int s0 = src_edges[e + 0], s1 = src_edges[e + 1];
    int s2 = src_edges[e + 2], s3 = src_edges[e + 3];
    uint2 q0 = *reinterpret_cast<const uint2*>(base + (size_t)s0 * D);
    uint2 q1 = *reinterpret_cast<const uint2*>(base + (size_t)s1 * D);
    uint2 q2 = *reinterpret_cast<const uint2*>(base + (size_t)s2 * D);
    uint2 q3 = *reinterpret_cast<const uint2*>(base + (size_t)s3 * D);
    float c0 = ysc[s0], c1 = ysc[s1], c2 = ysc[s2], c3 = ysc[s3];
    ACCQ(q0, c0); ACCQ(q1, c1); ACCQ(q2, c2); ACCQ(q3, c3);
  }
  for (; e < e1; ++e) {
    int s = src_edges[e];
    uint2 q = *reinterpret_cast<const uint2*>(base + (size_t)s * D);
    float c = ysc[s];
    ACCQ(q, c);
  }
  float nd = dst_norm[node];
  f32x4 o0 = {a0 * nd, a1 * nd, a2 * nd, a3 * nd};
  f32x4 o1 = {a4 * nd, a5 * nd, a6 * nd, a7 * nd};
  float* dst = out + (size_t)node * D + fo;
  __builtin_nontemporal_store(o0, reinterpret_cast<f32x4*>(dst));
  __builtin_nontemporal_store(o1, reinterpret_cast<f32x4*>(dst + 4));
}

// ---------- f32 fallback path (known-good) ----------

__global__ __launch_bounds__(256) void agg_kernel(
    const int* __restrict__ edge_ptr, const int* __restrict__ src_edges,
    const float* __restrict__ src_norm, const float* __restrict__ dst_norm,
    const float* __restrict__ X, float* __restrict__ agg, int n_nodes) {
  int gid = blockIdx.x * 256 + threadIdx.x;
  int node = gid >> 5;
  if (node >= n_nodes) return;
  int fo = (gid & 31) << 2;
  int e0 = edge_ptr[node];
  int e1 = edge_ptr[node + 1];
  float ax = 0.f, ay = 0.f, az = 0.f, aw = 0.f;
  for (int e = e0; e < e1; ++e) {
    int s = src_edges[e];
    float ns = src_norm[s];
    float4 v = *reinterpret_cast<const float4*>(X + (size_t)s * D + fo);
    ax = fmaf(ns, v.x, ax); ay = fmaf(ns, v.y, ay);
    az = fmaf(ns, v.z, az); aw = fmaf(ns, v.w, aw);
  }
  float nd = dst_norm[node];
  float4 r = make_float4(ax * nd, ay * nd, az * nd, aw * nd);
  *reinterpret_cast<float4*>(agg + (size_t)node * D + fo) = r;
}

#define FMA4(acc, sv, wv)            \
  acc.x = fmaf(sv, wv.x, acc.x);     \
  acc.y = fmaf(sv, wv.y, acc.y);     \
  acc.z = fmaf(sv, wv.z, acc.z);     \
  acc.w = fmaf(sv, wv.w, acc.w);

__global__ __launch_bounds__(256) void gemm_kernel(
    float* __restrict__ io, const float* __restrict__ W, int n_rows) {
  __shared__ float Wl[D][D];
  __shared__ float Al[TM][D];
  int tid = threadIdx.x;
  for (int i = tid * 4; i < D * D; i += 1024) {
    *reinterpret_cast<float4*>(&Wl[0][0] + i) =
        *reinterpret_cast<const float4*>(W + i);
  }
  int row0 = blockIdx.x * TM;
  for (int i = tid * 4; i < TM * D; i += 1024) {
    int r = i >> 7, c = i & (D - 1);
    if (row0 + r < n_rows)
      *reinterpret_cast<float4*>(&Al[r][c]) =
          *reinterpret_cast<const float4*>(io + (size_t)(row0 + r) * D + c);
  }
  __syncthreads();

  int cg = (tid & 31) * 4;
  int rb = (tid >> 5) * 4;
  float4 acc0 = {0, 0, 0, 0}, acc1 = {0, 0, 0, 0};
  float4 acc2 = {0, 0, 0, 0}, acc3 = {0, 0, 0, 0};

#pragma unroll 4
  for (int k = 0; k < D; k += 4) {
    float4 w0 = *reinterpret_cast<const float4*>(&Wl[k + 0][cg]);
    float4 w1 = *reinterpret_cast<const float4*>(&Wl[k + 1][cg]);
    float4 w2 = *reinterpret_cast<const float4*>(&Wl[k + 2][cg]);
    float4 w3 = *reinterpret_cast<const float4*>(&Wl[k + 3][cg]);
    float4 a0 = *reinterpret_cast<const float4*>(&Al[rb + 0][k]);
    float4 a1 = *reinterpret_cast<const float4*>(&Al[rb + 1][k]);
    float4 a2 = *reinterpret_cast<const float4*>(&Al[rb + 2][k]);
    float4 a3 = *reinterpret_cast<const float4*>(&Al[rb + 3][k]);
    FMA4(acc0, a0.x, w0); FMA4(acc0, a0.y, w1); FMA4(acc0, a0.z, w2); FMA4(acc0, a0.w, w3);
    FMA4(acc1, a1.x, w0); FMA4(acc1, a1.y, w1); FMA4(acc1, a1.z, w2); FMA4(acc1, a1.w, w3);
    FMA4(acc2, a2.x, w0); FMA4(acc2, a2.y, w1); FMA4(acc2, a2.z, w2); FMA4(acc2, a2.w, w3);
    FMA4(acc3, a3.x, w0); FMA4(acc3, a3.y, w1); FMA4(acc3, a3.z, w2); FMA4(acc3, a3.w, w3);
  }

  int r0 = row0 + rb;
  if (r0 + 0 < n_rows) *reinterpret_cast<float4*>(io + (size_t)(r0 + 0) * D + cg) = acc0;
  if (r0 + 1 < n_rows) *reinterpret_cast<float4*>(io + (size_t)(r0 + 1) * D + cg) = acc1;
  if (r0 + 2 < n_rows) *reinterpret_cast<float4*>(io + (size_t)(r0 + 2) * D + cg) = acc2;
  if (r0 + 3 < n_rows) *reinterpret_cast<float4*>(io + (size_t)(r0 + 3) * D + cg) = acc3;
}

extern "C" void kernel_launch(void* const* d_in, const int* in_sizes, int n_in,
                              void* d_out, int out_size, void* d_ws, size_t ws_size,
                              hipStream_t stream) {
  const int* edge_ptr = (const int*)d_in[0];
  const int* src_edges = (const int*)d_in[1];
  const float* src_norm = (const float*)d_in[2];
  const float* dst_norm = (const float*)d_in[3];
  const float* X = (const float*)d_in[5];
  const float* W = (const float*)d_in[6];
  float* out = (float*)d_out;
  int n = in_sizes[2];  // src_norm_degs has N elements

  size_t need = (size_t)n * D + (size_t)n * sizeof(float) +
                (size_t)D * D * sizeof(u16);
  if (ws_size >= need) {
    signed char* Yq = (signed char*)d_ws;
    float* ysc = (float*)(Yq + (size_t)n * D);
    u16* Wt = (u16*)(ysc + n);
    cvt_w<<<(D * D + 255) / 256, 256, 0, stream>>>(W, Wt);
    gemm_xw<<<(n + 63) / 64, 256, 0, stream>>>(X, src_norm, Wt, Yq, ysc, n);
    agg_final<<<(n * 16 + 255) / 256, 256, 0, stream>>>(edge_ptr, src_edges,
                                                        dst_norm, Yq, ysc, out, n);
  } else {
    int blocks1 = (n * 32 + 255) / 256;
    agg_kernel<<<blocks1, 256, 0, stream>>>(edge_ptr, src_edges, src_norm,
                                            dst_norm, X, out, n);
    int blocks2 = (n + TM - 1) / TM;
    gemm_kernel<<<blocks2, 256, 0, stream>>>(out, W, n);
  }
}